// Round 7
// baseline (304.638 us; speedup 1.0000x reference)
//
#include <hip/hip_runtime.h>
#include <hip/hip_bf16.h>
#include <stdint.h>

#define D_MODEL 1024
#define NHEAD   16
#define DH      64

typedef __attribute__((ext_vector_type(8))) short bf16x8;
typedef __attribute__((ext_vector_type(4))) float f32x4;

__device__ __forceinline__ ushort f2bf(float f) {
    __hip_bfloat16 h = __float2bfloat16(f);
    return *reinterpret_cast<ushort*>(&h);
}

__device__ __forceinline__ void gload_lds16(const void* g, void* l) {
    __builtin_amdgcn_global_load_lds(
        (const __attribute__((address_space(1))) void*)g,
        (__attribute__((address_space(3))) void*)l, 16, 0, 0);
}

// Load 8 contiguous fp32, convert to bf16x8 in-register.
__device__ __forceinline__ bf16x8 load8f(const float* p) {
    const float4 a = *(const float4*)p;
    const float4 b = *(const float4*)(p + 4);
    bf16x8 r;
    r[0] = (short)f2bf(a.x); r[1] = (short)f2bf(a.y);
    r[2] = (short)f2bf(a.z); r[3] = (short)f2bf(a.w);
    r[4] = (short)f2bf(b.x); r[5] = (short)f2bf(b.y);
    r[6] = (short)f2bf(b.z); r[7] = (short)f2bf(b.w);
    return r;
}

// fp32 -> bf16 weight conversion only (fallback path).
__global__ __launch_bounds__(256) void cvt_w_kernel(
    const float* __restrict__ w0, const float* __restrict__ w1,
    const float* __restrict__ w2, const float* __restrict__ w3,
    ushort* __restrict__ out)
{
    const int g = blockIdx.x * 256 + threadIdx.x;
    const int m = g >> 17;
    const int off = (g & 131071) * 8;
    const float* src = (m == 0) ? w0 : (m == 1) ? w1 : (m == 2) ? w2 : w3;
    *(bf16x8*)(out + (size_t)m * 1048576 + off) = load8f(src + off);
}

// Combined weights + inputs conversion (ext path): one launch, one gap.
__global__ __launch_bounds__(256) void cvt_all_kernel(
    const float* __restrict__ w0, const float* __restrict__ w1,
    const float* __restrict__ w2, const float* __restrict__ w3,
    const float* __restrict__ X0, const float* __restrict__ X1,
    const float* __restrict__ X2,
    ushort* __restrict__ Wb,
    ushort* __restrict__ Qb, ushort* __restrict__ Kb, ushort* __restrict__ Vb,
    int igrp)   // groups of 8 per input matrix
{
    const int g = blockIdx.x * 256 + threadIdx.x;
    if (g < 524288) {                    // 4 weight matrices, 131072 groups each
        const int m = g >> 17;
        const int off = (g & 131071) * 8;
        const float* src = (m == 0) ? w0 : (m == 1) ? w1 : (m == 2) ? w2 : w3;
        *(bf16x8*)(Wb + (size_t)m * 1048576 + off) = load8f(src + off);
    } else {
        const int g2 = g - 524288;
        if (g2 >= 3 * igrp) return;
        const int m = g2 / igrp;
        const int off = (g2 - m * igrp) * 8;
        const float* src = (m == 0) ? X0 : (m == 1) ? X1 : X2;
        ushort* dst = (m == 0) ? Qb : (m == 1) ? Kb : Vb;
        *(bf16x8*)(dst + off) = load8f(src + off);
    }
}

// ---- shared GEMM epilogue helpers ----
__device__ __forceinline__ void storeC(float*  C, size_t i, float v) { C[i] = v; }
__device__ __forceinline__ void storeC(ushort* C, size_t i, float v) { C[i] = (short)f2bf(v); }

__device__ __forceinline__ void xcd_swizzle(int& bx, int& by) {
    if (gridDim.x == 8 && (gridDim.y & 7) == 0) {
        const int fid   = by * 8 + bx;
        const int xcd   = fid & 7;
        const int local = fid >> 3;
        const int rpx   = gridDim.y >> 3;
        by = xcd * rpx + (local >> 3);
        bx = local & 7;
    }
}

// C = scale * (X(MxK) @ Wb^T + bias). R5-proven structure (BK=32,
// __syncthreads x2 per step). Pipelining attempts (R1 drain-form, R6
// counted-vmcnt) were regressive/neutral: at 3 blocks/CU the implicit
// inter-block wave overlap already hides staging latency.
template<int NW, bool A_F32, typename TX, typename TOUT>
__device__ __forceinline__ void gemm_core(
    const TX* __restrict__ X,
    const ushort* __restrict__ Wb,
    const float* __restrict__ Bias,
    TOUT* __restrict__ C,
    int M, int N, int K, float scale,
    short* As, short* Bs)
{
    const int tid  = threadIdx.x;
    const int w    = tid >> 6;
    const int lane = tid & 63;
    const int quad = lane >> 4;
    const int l15  = lane & 15;
    const int wr   = (NW == 4) ? (w >> 1) : (w >> 2);
    const int wc   = (NW == 4) ? (w & 1)  : (w & 3);
    const int NJ   = (NW == 4) ? 4 : 2;
    const int colw = (NW == 4) ? 64 : 32;

    int bx = blockIdx.x, by = blockIdx.y;
    xcd_swizzle(bx, by);
    const int m0 = by * 128;
    const int n0 = bx * 128;

    f32x4 acc[4][4] = {};

    for (int k0 = 0; k0 < K; k0 += 32) {
        __syncthreads();
        #pragma unroll
        for (int c = 0; c < 8 / NW; ++c) {
            int chunk = w * (8 / NW) + c;
            int row   = chunk * 16 + (lane >> 2);
            gload_lds16(Wb + (size_t)(n0 + row) * K + k0 + (lane & 3) * 8,
                        &Bs[chunk * 512]);
        }
        if constexpr (A_F32) {
            #pragma unroll
            for (int c = 0; c < 2; ++c) {
                int idx = c * 256 + tid;
                int row = idx >> 2;
                int col = (idx & 3) * 8;
                *(bf16x8*)&As[row * 32 + col] =
                    load8f((const float*)X + (size_t)(m0 + row) * K + k0 + col);
            }
        } else {
            #pragma unroll
            for (int c = 0; c < 8 / NW; ++c) {
                int chunk = w * (8 / NW) + c;
                int row   = chunk * 16 + (lane >> 2);
                gload_lds16((const ushort*)X + (size_t)(m0 + row) * K + k0 + (lane & 3) * 8,
                            &As[chunk * 512]);
            }
        }
        __syncthreads();

        bf16x8 af[4], bfr[4];
        #pragma unroll
        for (int i = 0; i < 4; ++i)
            af[i] = *(const bf16x8*)&As[(wr * 64 + i * 16 + l15) * 32 + quad * 8];
        #pragma unroll
        for (int j = 0; j < NJ; ++j)
            bfr[j] = *(const bf16x8*)&Bs[(wc * colw + j * 16 + l15) * 32 + quad * 8];
        #pragma unroll
        for (int i = 0; i < 4; ++i)
            #pragma unroll
            for (int j = 0; j < NJ; ++j)
                acc[i][j] = __builtin_amdgcn_mfma_f32_16x16x32_bf16(af[i], bfr[j], acc[i][j], 0, 0, 0);
    }

    float bias[4];
    #pragma unroll
    for (int j = 0; j < NJ; ++j)
        bias[j] = Bias[n0 + wc * colw + j * 16 + l15];

    #pragma unroll
    for (int i = 0; i < 4; ++i) {
        int row = m0 + wr * 64 + i * 16 + quad * 4;
        #pragma unroll
        for (int j = 0; j < NJ; ++j) {
            int col = n0 + wc * colw + j * 16 + l15;
            #pragma unroll
            for (int r = 0; r < 4; ++r)
                storeC(C, (size_t)(row + r) * N + col, (acc[i][j][r] + bias[j]) * scale);
        }
    }
}

__global__ __launch_bounds__(256) void qkv_proj_f32_kernel(
    const float* __restrict__ Qin, const float* __restrict__ Kin,
    const float* __restrict__ Vin,
    const ushort* __restrict__ Wb,
    const float* __restrict__ Bq, const float* __restrict__ Bk,
    const float* __restrict__ Bv,
    ushort* qo, ushort* ko, ushort* vo, int L)
{
    __shared__ short As[4096];
    __shared__ short Bs[4096];
    const int z = blockIdx.z;
    const float *X, *B; ushort* C;
    float scale = 1.0f;
    if (z == 0)      { X = Qin; B = Bq; C = qo; scale = 0.125f * 1.44269504088896f; }
    else if (z == 1) { X = Kin; B = Bk; C = ko; }
    else             { X = Vin; B = Bv; C = vo; }
    gemm_core<4, true, float, ushort>(X, Wb + (size_t)z * 1048576, B, C,
                                      L, D_MODEL, D_MODEL, scale, As, Bs);
}

__global__ __launch_bounds__(256) void qkv_proj_bf16_kernel(
    const ushort* __restrict__ Qb, const ushort* __restrict__ Kb,
    const ushort* __restrict__ Vb,
    const ushort* __restrict__ Wb,
    const float* __restrict__ Bq, const float* __restrict__ Bk,
    const float* __restrict__ Bv,
    ushort* qo, ushort* ko, ushort* vo, int L)
{
    __shared__ short As[4096];
    __shared__ short Bs[4096];
    const int z = blockIdx.z;
    const ushort *X; const float* B; ushort* C;
    float scale = 1.0f;
    if (z == 0)      { X = Qb; B = Bq; C = qo; scale = 0.125f * 1.44269504088896f; }
    else if (z == 1) { X = Kb; B = Bk; C = ko; }
    else             { X = Vb; B = Bv; C = vo; }
    gemm_core<4, false, ushort, ushort>(X, Wb + (size_t)z * 1048576, B, C,
                                        L, D_MODEL, D_MODEL, scale, As, Bs);
}

__global__ __launch_bounds__(512) void out_proj_kernel(
    const ushort* __restrict__ Xa, const ushort* __restrict__ Wb,
    const float* __restrict__ Bo, float* out, int L)
{
    __shared__ short As[4096];
    __shared__ short Bs[4096];
    gemm_core<8, false, ushort, float>(Xa, Wb + (size_t)3 * 1048576, Bo, out,
                                       L, D_MODEL, D_MODEL, 1.0f, As, Bs);
}

// Flash attention, transposed-score form.
// R7: KVBLK 64 -> 128. Two 64-key sub-tiles per barrier interval: halves
// barrier-drains, loop/prefetch overhead, max-reduce shuffles; ONE defer-max
// branch + at most one O-rescale per 128 keys. l-reduction deferred to the
// epilogue (alpha is quad-uniform per q-row, so per-quad partials scale
// identically) — removes all per-tile l shuffles. LDS 48 KB, still 2
// blocks/CU (grid-limited). PV runs as two passes reusing the per-wave Ps.
__global__ __launch_bounds__(512) void attn_kernel(
    const ushort* __restrict__ Qw,
    const ushort* __restrict__ Kw,
    const ushort* __restrict__ Vw,
    ushort* __restrict__ Ow, int L)
{
    __shared__ short Ks[128 * 64];     // [key][d] XOR-swizzled, 16 KB
    __shared__ short Vs[64 * 128];     // [d][key] XOR-swizzled, 16 KB
    __shared__ short Ps[8][16 * 64];   // per-wave P tile (one 64-key pass)

    const int tid  = threadIdx.x;
    const int w    = tid >> 6;
    const int lane = tid & 63;
    const int quad = lane >> 4;
    const int l15  = lane & 15;
    const int h    = blockIdx.y;
    const int q0   = blockIdx.x * 128;

    const ushort* qp = Qw + (size_t)(q0 + w * 16 + l15) * D_MODEL + h * DH + quad * 8;
    bf16x8 qf0 = *(const bf16x8*)(qp);
    bf16x8 qf1 = *(const bf16x8*)(qp + 32);

    const int kkey = tid >> 3;         // 0..63 (first key half; +64 second)
    const int kc8  = tid & 7;
    const int vkey = lane;             // key 0..63 (first half; +64 second)
    const int vdh  = w * 8;            // 8 d-rows per wave

    const int krswz0 = ((quad    ) ^ (l15 & 7)) * 8;
    const int krswz1 = ((quad + 4) ^ (l15 & 7)) * 8;

    // K write offset (key row & 7 invariant under +64)
    const int kwofs = kkey * 64 + ((kc8 ^ (kkey & 7)) * 8);
    const int vkb   = vkey >> 3;       // key-block 0..7
    const int vk7   = vkey & 7;

    f32x4 o[4] = {};
    float m_run = -3e38f, l_run = 0.f;
    const float thr = 8.0f;            // defer-max threshold (exp2 domain)

    const ushort* kptr0 = Kw + (size_t)kkey * D_MODEL + h * DH + kc8 * 8;
    const ushort* kptr1 = kptr0 + (size_t)64 * D_MODEL;
    const ushort* vptr0 = Vw + (size_t)vkey * D_MODEL + h * DH + vdh;
    const ushort* vptr1 = vptr0 + (size_t)64 * D_MODEL;
    bf16x8 kreg0 = *(const bf16x8*)kptr0;
    bf16x8 kreg1 = *(const bf16x8*)kptr1;
    bf16x8 vreg0 = *(const bf16x8*)vptr0;
    bf16x8 vreg1 = *(const bf16x8*)vptr1;

    for (int key0 = 0; key0 < L; key0 += 128) {
        __syncthreads();   // WAR: previous tile's LDS reads done
        *(bf16x8*)&Ks[kwofs] = kreg0;
        *(bf16x8*)&Ks[kwofs + 64 * 64] = kreg1;
        #pragma unroll
        for (int i = 0; i < 8; ++i) {
            const int b = (vdh + i) * 128 + ((vkb ^ i) * 8) + vk7;
            Vs[b]      = vreg0[i];
            Vs[b + 64] = vreg1[i];
        }
        __syncthreads();

        if (key0 + 128 < L) {   // prefetch next 128-key tile during compute
            kptr0 += (size_t)128 * D_MODEL;  kptr1 += (size_t)128 * D_MODEL;
            vptr0 += (size_t)128 * D_MODEL;  vptr1 += (size_t)128 * D_MODEL;
            kreg0 = *(const bf16x8*)kptr0;   kreg1 = *(const bf16x8*)kptr1;
            vreg0 = *(const bf16x8*)vptr0;   vreg1 = *(const bf16x8*)vptr1;
        }

        f32x4 st[8];
        __builtin_amdgcn_s_setprio(1);
        #pragma unroll
        for (int kt = 0; kt < 8; ++kt) {
            const int kr = (kt * 16 + l15) * 64;
            bf16x8 kf0 = *(const bf16x8*)&Ks[kr + krswz0];
            bf16x8 kf1 = *(const bf16x8*)&Ks[kr + krswz1];
            f32x4 z = {};
            z = __builtin_amdgcn_mfma_f32_16x16x32_bf16(kf0, qf0, z, 0, 0, 0);
            z = __builtin_amdgcn_mfma_f32_16x16x32_bf16(kf1, qf1, z, 0, 0, 0);
            st[kt] = z;
        }
        __builtin_amdgcn_s_setprio(0);

        float mx = st[0][0];
        #pragma unroll
        for (int kt = 0; kt < 8; ++kt)
            #pragma unroll
            for (int r = 0; r < 4; ++r)
                mx = fmaxf(mx, st[kt][r]);
        mx = fmaxf(mx, __shfl_xor(mx, 16));
        mx = fmaxf(mx, __shfl_xor(mx, 32));

        if (!__all(mx <= m_run + thr)) {
            const float mnew  = fmaxf(m_run, mx);
            const float alpha = __builtin_amdgcn_exp2f(m_run - mnew);
            m_run = mnew;
            l_run *= alpha;          // per-quad partial; alpha is q-row-uniform
            float a[4];
            #pragma unroll
            for (int r = 0; r < 4; ++r)
                a[r] = __shfl(alpha, (lane & 48) | (quad * 4 + r));
            #pragma unroll
            for (int dt = 0; dt < 4; ++dt)
                #pragma unroll
                for (int r = 0; r < 4; ++r)
                    o[dt][r] *= a[r];
        }

        #pragma unroll
        for (int p = 0; p < 2; ++p) {
            float rs = 0.f;
            #pragma unroll
            for (int kt = 0; kt < 4; ++kt) {
                const f32x4 s = st[p * 4 + kt];
                float p0 = __builtin_amdgcn_exp2f(s[0] - m_run);
                float p1 = __builtin_amdgcn_exp2f(s[1] - m_run);
                float p2 = __builtin_amdgcn_exp2f(s[2] - m_run);
                float p3 = __builtin_amdgcn_exp2f(s[3] - m_run);
                rs += (p0 + p1) + (p2 + p3);
                uint2 pk;
                pk.x = (uint32_t)f2bf(p0) | ((uint32_t)f2bf(p1) << 16);
                pk.y = (uint32_t)f2bf(p2) | ((uint32_t)f2bf(p3) << 16);
                const int G = kt * 2 + (quad >> 1);
                *(uint2*)&Ps[w][l15 * 64 + ((G ^ (l15 & 7)) * 8) + (quad & 1) * 4] = pk;
            }
            l_run += rs;             // deferred reduce: per-quad partial only

            __builtin_amdgcn_s_setprio(1);
            #pragma unroll
            for (int f = 0; f < 2; ++f) {
                bf16x8 pf = *(const bf16x8*)&Ps[w][l15 * 64 + (((f * 4 + quad) ^ (l15 & 7)) * 8)];
                #pragma unroll
                for (int dt = 0; dt < 4; ++dt) {
                    bf16x8 vf = *(const bf16x8*)&Vs[(dt * 16 + l15) * 128 +
                                                    (((f * 4 + quad) ^ (l15 & 7)) * 8) + p * 64];
                    o[dt] = __builtin_amdgcn_mfma_f32_16x16x32_bf16(pf, vf, o[dt], 0, 0, 0);
                }
            }
            __builtin_amdgcn_s_setprio(0);
        }
    }

    // epilogue: reduce the deferred per-quad l partials, then normalize
    l_run += __shfl_xor(l_run, 16);
    l_run += __shfl_xor(l_run, 32);
    const float inv = 1.f / l_run;
    #pragma unroll
    for (int r = 0; r < 4; ++r) {
        const float linv = __shfl(inv, (lane & 48) | (quad * 4 + r));
        const int row = q0 + w * 16 + quad * 4 + r;
        #pragma unroll
        for (int dt = 0; dt < 4; ++dt) {
            int col = h * DH + dt * 16 + l15;
            Ow[(size_t)row * D_MODEL + col] = (short)f2bf(o[dt][r] * linv);
        }
    }
}

extern "C" void kernel_launch(void* const* d_in, const int* in_sizes, int n_in,
                              void* d_out, int out_size, void* d_ws, size_t ws_size,
                              hipStream_t stream) {
    const float* Q   = (const float*)d_in[0];
    const float* K   = (const float*)d_in[1];
    const float* V   = (const float*)d_in[2];
    const float* w_q = (const float*)d_in[3];
    const float* b_q = (const float*)d_in[4];
    const float* w_k = (const float*)d_in[5];
    const float* b_k = (const float*)d_in[6];
    const float* w_v = (const float*)d_in[7];
    const float* b_v = (const float*)d_in[8];
    const float* w_o = (const float*)d_in[9];
    const float* b_o = (const float*)d_in[10];
    float* out = (float*)d_out;

    const int L = in_sizes[0] / D_MODEL;   // 4096
    const size_t mat = (size_t)L * D_MODEL;

    // Memory plan.
    // Fallback (ws >= 24 MB): d_ws [0,8): Wb | [8,16): a_ws | [16,24): v_ws;
    //   d_out [0,8): q_ws | [8,16): k_ws (dead before out_proj's fp32 C).
    // Extended (ws >= 40 MB, confirmed active since R5):
    //   d_ws [0,8): Wb | [8,16): Vb -> a_ws | [16,24): v_ws |
    //        [24,32): Qb | [32,40): Kb
    ushort* Wb   = (ushort*)d_ws;
    ushort* q_ws = (ushort*)d_out;
    ushort* k_ws = q_ws + mat;
    const bool ext = ws_size >= (size_t)40 * 1024 * 1024;

    ushort *a_ws, *v_ws, *Qb = nullptr, *Kb = nullptr, *Vb = nullptr;
    if (ext) {
        Vb   = (ushort*)d_ws + 4 * 1048576;   // [8,16)
        v_ws = Vb + mat;                      // [16,24)
        Qb   = v_ws + mat;                    // [24,32)
        Kb   = Qb + mat;                      // [32,40)
        a_ws = Vb;                            // reuse after qkv consumes Vb
    } else {
        a_ws = (ushort*)d_ws + 4 * 1048576;
        v_ws = a_ws + mat;
    }

    dim3 gqkv(D_MODEL / 128, L / 128, 3);
    if (ext) {
        const int igrp = (int)(mat / 8);
        const int total = 524288 + 3 * igrp;
        cvt_all_kernel<<<dim3((total + 255) / 256), dim3(256), 0, stream>>>(
            w_q, w_k, w_v, w_o, Q, K, V, Wb, Qb, Kb, Vb, igrp);
        qkv_proj_bf16_kernel<<<gqkv, dim3(256), 0, stream>>>(Qb, Kb, Vb, Wb,
                                                             b_q, b_k, b_v,
                                                             q_ws, k_ws, v_ws, L);
    } else {
        cvt_w_kernel<<<dim3(2048), dim3(256), 0, stream>>>(w_q, w_k, w_v, w_o, Wb);
        qkv_proj_f32_kernel<<<gqkv, dim3(256), 0, stream>>>(Q, K, V, Wb,
                                                            b_q, b_k, b_v,
                                                            q_ws, k_ws, v_ws, L);
    }
    dim3 gattn(L / 128, NHEAD);
    attn_kernel<<<gattn, dim3(512), 0, stream>>>(q_ws, k_ws, v_ws, a_ws, L);
    dim3 gout(D_MODEL / 128, L / 128);
    out_proj_kernel<<<gout, dim3(512), 0, stream>>>(a_ws, Wb, b_o, out, L);
}

// Round 8
// 277.517 us; speedup vs baseline: 1.0977x; 1.0977x over previous
//
#include <hip/hip_runtime.h>
#include <hip/hip_bf16.h>
#include <stdint.h>

#define D_MODEL 1024
#define NHEAD   16
#define DH      64

typedef __attribute__((ext_vector_type(8))) short bf16x8;
typedef __attribute__((ext_vector_type(4))) float f32x4;

__device__ __forceinline__ ushort f2bf(float f) {
    __hip_bfloat16 h = __float2bfloat16(f);
    return *reinterpret_cast<ushort*>(&h);
}

__device__ __forceinline__ void gload_lds16(const void* g, void* l) {
    __builtin_amdgcn_global_load_lds(
        (const __attribute__((address_space(1))) void*)g,
        (__attribute__((address_space(3))) void*)l, 16, 0, 0);
}

// Load 8 contiguous fp32, convert to bf16x8 in-register.
__device__ __forceinline__ bf16x8 load8f(const float* p) {
    const float4 a = *(const float4*)p;
    const float4 b = *(const float4*)(p + 4);
    bf16x8 r;
    r[0] = (short)f2bf(a.x); r[1] = (short)f2bf(a.y);
    r[2] = (short)f2bf(a.z); r[3] = (short)f2bf(a.w);
    r[4] = (short)f2bf(b.x); r[5] = (short)f2bf(b.y);
    r[6] = (short)f2bf(b.z); r[7] = (short)f2bf(b.w);
    return r;
}

// fp32 -> bf16 weight conversion only (fallback path).
__global__ __launch_bounds__(256) void cvt_w_kernel(
    const float* __restrict__ w0, const float* __restrict__ w1,
    const float* __restrict__ w2, const float* __restrict__ w3,
    ushort* __restrict__ out)
{
    const int g = blockIdx.x * 256 + threadIdx.x;
    const int m = g >> 17;
    const int off = (g & 131071) * 8;
    const float* src = (m == 0) ? w0 : (m == 1) ? w1 : (m == 2) ? w2 : w3;
    *(bf16x8*)(out + (size_t)m * 1048576 + off) = load8f(src + off);
}

// Combined weights + inputs conversion (ext path): one launch, one gap.
__global__ __launch_bounds__(256) void cvt_all_kernel(
    const float* __restrict__ w0, const float* __restrict__ w1,
    const float* __restrict__ w2, const float* __restrict__ w3,
    const float* __restrict__ X0, const float* __restrict__ X1,
    const float* __restrict__ X2,
    ushort* __restrict__ Wb,
    ushort* __restrict__ Qb, ushort* __restrict__ Kb, ushort* __restrict__ Vb,
    int igrp)   // groups of 8 per input matrix
{
    const int g = blockIdx.x * 256 + threadIdx.x;
    if (g < 524288) {                    // 4 weight matrices, 131072 groups each
        const int m = g >> 17;
        const int off = (g & 131071) * 8;
        const float* src = (m == 0) ? w0 : (m == 1) ? w1 : (m == 2) ? w2 : w3;
        *(bf16x8*)(Wb + (size_t)m * 1048576 + off) = load8f(src + off);
    } else {
        const int g2 = g - 524288;
        if (g2 >= 3 * igrp) return;
        const int m = g2 / igrp;
        const int off = (g2 - m * igrp) * 8;
        const float* src = (m == 0) ? X0 : (m == 1) ? X1 : X2;
        ushort* dst = (m == 0) ? Qb : (m == 1) ? Kb : Vb;
        *(bf16x8*)(dst + off) = load8f(src + off);
    }
}

// ---- shared GEMM epilogue helpers ----
__device__ __forceinline__ void storeC(float*  C, size_t i, float v) { C[i] = v; }
__device__ __forceinline__ void storeC(ushort* C, size_t i, float v) { C[i] = (short)f2bf(v); }

__device__ __forceinline__ void xcd_swizzle(int& bx, int& by) {
    if (gridDim.x == 8 && (gridDim.y & 7) == 0) {
        const int fid   = by * 8 + bx;
        const int xcd   = fid & 7;
        const int local = fid >> 3;
        const int rpx   = gridDim.y >> 3;
        by = xcd * rpx + (local >> 3);
        bx = local & 7;
    }
}

// C = scale * (X(MxK) @ Wb^T + bias). R5-proven structure (BK=32,
// __syncthreads x2 per step). Pipelining attempts (R1 drain-form, R6
// counted-vmcnt) regressive/neutral; BK=64 (R4) neutral: at 3 blocks/CU the
// implicit inter-block wave overlap already hides staging latency.
template<int NW, bool A_F32, typename TX, typename TOUT>
__device__ __forceinline__ void gemm_core(
    const TX* __restrict__ X,
    const ushort* __restrict__ Wb,
    const float* __restrict__ Bias,
    TOUT* __restrict__ C,
    int M, int N, int K, float scale,
    short* As, short* Bs)
{
    const int tid  = threadIdx.x;
    const int w    = tid >> 6;
    const int lane = tid & 63;
    const int quad = lane >> 4;
    const int l15  = lane & 15;
    const int wr   = (NW == 4) ? (w >> 1) : (w >> 2);
    const int wc   = (NW == 4) ? (w & 1)  : (w & 3);
    const int NJ   = (NW == 4) ? 4 : 2;
    const int colw = (NW == 4) ? 64 : 32;

    int bx = blockIdx.x, by = blockIdx.y;
    xcd_swizzle(bx, by);
    const int m0 = by * 128;
    const int n0 = bx * 128;

    f32x4 acc[4][4] = {};

    for (int k0 = 0; k0 < K; k0 += 32) {
        __syncthreads();
        #pragma unroll
        for (int c = 0; c < 8 / NW; ++c) {
            int chunk = w * (8 / NW) + c;
            int row   = chunk * 16 + (lane >> 2);
            gload_lds16(Wb + (size_t)(n0 + row) * K + k0 + (lane & 3) * 8,
                        &Bs[chunk * 512]);
        }
        if constexpr (A_F32) {
            #pragma unroll
            for (int c = 0; c < 2; ++c) {
                int idx = c * 256 + tid;
                int row = idx >> 2;
                int col = (idx & 3) * 8;
                *(bf16x8*)&As[row * 32 + col] =
                    load8f((const float*)X + (size_t)(m0 + row) * K + k0 + col);
            }
        } else {
            #pragma unroll
            for (int c = 0; c < 8 / NW; ++c) {
                int chunk = w * (8 / NW) + c;
                int row   = chunk * 16 + (lane >> 2);
                gload_lds16((const ushort*)X + (size_t)(m0 + row) * K + k0 + (lane & 3) * 8,
                            &As[chunk * 512]);
            }
        }
        __syncthreads();

        bf16x8 af[4], bfr[4];
        #pragma unroll
        for (int i = 0; i < 4; ++i)
            af[i] = *(const bf16x8*)&As[(wr * 64 + i * 16 + l15) * 32 + quad * 8];
        #pragma unroll
        for (int j = 0; j < NJ; ++j)
            bfr[j] = *(const bf16x8*)&Bs[(wc * colw + j * 16 + l15) * 32 + quad * 8];
        #pragma unroll
        for (int i = 0; i < 4; ++i)
            #pragma unroll
            for (int j = 0; j < NJ; ++j)
                acc[i][j] = __builtin_amdgcn_mfma_f32_16x16x32_bf16(af[i], bfr[j], acc[i][j], 0, 0, 0);
    }

    float bias[4];
    #pragma unroll
    for (int j = 0; j < NJ; ++j)
        bias[j] = Bias[n0 + wc * colw + j * 16 + l15];

    #pragma unroll
    for (int i = 0; i < 4; ++i) {
        int row = m0 + wr * 64 + i * 16 + quad * 4;
        #pragma unroll
        for (int j = 0; j < NJ; ++j) {
            int col = n0 + wc * colw + j * 16 + l15;
            #pragma unroll
            for (int r = 0; r < 4; ++r)
                storeC(C, (size_t)(row + r) * N + col, (acc[i][j][r] + bias[j]) * scale);
        }
    }
}

__global__ __launch_bounds__(256) void qkv_proj_f32_kernel(
    const float* __restrict__ Qin, const float* __restrict__ Kin,
    const float* __restrict__ Vin,
    const ushort* __restrict__ Wb,
    const float* __restrict__ Bq, const float* __restrict__ Bk,
    const float* __restrict__ Bv,
    ushort* qo, ushort* ko, ushort* vo, int L)
{
    __shared__ short As[4096];
    __shared__ short Bs[4096];
    const int z = blockIdx.z;
    const float *X, *B; ushort* C;
    float scale = 1.0f;
    if (z == 0)      { X = Qin; B = Bq; C = qo; scale = 0.125f * 1.44269504088896f; }
    else if (z == 1) { X = Kin; B = Bk; C = ko; }
    else             { X = Vin; B = Bv; C = vo; }
    gemm_core<4, true, float, ushort>(X, Wb + (size_t)z * 1048576, B, C,
                                      L, D_MODEL, D_MODEL, scale, As, Bs);
}

__global__ __launch_bounds__(256) void qkv_proj_bf16_kernel(
    const ushort* __restrict__ Qb, const ushort* __restrict__ Kb,
    const ushort* __restrict__ Vb,
    const ushort* __restrict__ Wb,
    const float* __restrict__ Bq, const float* __restrict__ Bk,
    const float* __restrict__ Bv,
    ushort* qo, ushort* ko, ushort* vo, int L)
{
    __shared__ short As[4096];
    __shared__ short Bs[4096];
    const int z = blockIdx.z;
    const ushort *X; const float* B; ushort* C;
    float scale = 1.0f;
    if (z == 0)      { X = Qb; B = Bq; C = qo; scale = 0.125f * 1.44269504088896f; }
    else if (z == 1) { X = Kb; B = Bk; C = ko; }
    else             { X = Vb; B = Bv; C = vo; }
    gemm_core<4, false, ushort, ushort>(X, Wb + (size_t)z * 1048576, B, C,
                                        L, D_MODEL, D_MODEL, scale, As, Bs);
}

__global__ __launch_bounds__(512) void out_proj_kernel(
    const ushort* __restrict__ Xa, const ushort* __restrict__ Wb,
    const float* __restrict__ Bo, float* out, int L)
{
    __shared__ short As[4096];
    __shared__ short Bs[4096];
    gemm_core<8, false, ushort, float>(Xa, Wb + (size_t)3 * 1048576, Bo, out,
                                       L, D_MODEL, D_MODEL, 1.0f, As, Bs);
}

// Flash attention, transposed-score form. R5/R6-proven structure (KVBLK=64,
// 2 barriers/tile, T14 reg-prefetch, T13 defer-max, T5 setprio, exp2-domain
// scores). R7's KVBLK=128 regressed (bank conflicts 3x, occupancy -16pt) —
// reverted. R8 keeps only R7's safe piece: DEFERRED l-reduction (alpha is
// q-row-uniform across quads, so per-quad partial l scales identically;
// the two per-tile shfl_xor move to the epilogue).
__global__ __launch_bounds__(512) void attn_kernel(
    const ushort* __restrict__ Qw,
    const ushort* __restrict__ Kw,
    const ushort* __restrict__ Vw,
    ushort* __restrict__ Ow, int L)
{
    __shared__ short Ks[64 * 64];
    __shared__ short Vs[64 * 64];
    __shared__ short Ps[8][16 * 64];

    const int tid  = threadIdx.x;
    const int w    = tid >> 6;
    const int lane = tid & 63;
    const int quad = lane >> 4;
    const int l15  = lane & 15;
    const int h    = blockIdx.y;
    const int q0   = blockIdx.x * 128;

    const ushort* qp = Qw + (size_t)(q0 + w * 16 + l15) * D_MODEL + h * DH + quad * 8;
    bf16x8 qf0 = *(const bf16x8*)(qp);
    bf16x8 qf1 = *(const bf16x8*)(qp + 32);

    const int kkey = tid >> 3;
    const int kc8  = tid & 7;
    const int vkey = lane;
    const int vdh  = w * 8;

    const int krswz0 = ((quad    ) ^ (l15 & 7)) * 8;
    const int krswz1 = ((quad + 4) ^ (l15 & 7)) * 8;

    f32x4 o[4] = {};
    float m_run = -3e38f, l_run = 0.f;
    const float thr = 8.0f;   // defer-max threshold (exp2 domain)

    const ushort* kptr = Kw + (size_t)kkey * D_MODEL + h * DH + kc8 * 8;
    const ushort* vptr = Vw + (size_t)vkey * D_MODEL + h * DH + vdh;
    bf16x8 kreg = *(const bf16x8*)kptr;
    bf16x8 vreg = *(const bf16x8*)vptr;

    for (int key0 = 0; key0 < L; key0 += 64) {
        __syncthreads();
        *(bf16x8*)&Ks[kkey * 64 + ((kc8 ^ (kkey & 7)) * 8)] = kreg;
        #pragma unroll
        for (int i = 0; i < 8; ++i)
            Vs[(vdh + i) * 64 + (((vkey >> 3) ^ i) * 8) + (vkey & 7)] = vreg[i];
        __syncthreads();

        if (key0 + 64 < L) {
            kptr += (size_t)64 * D_MODEL;
            vptr += (size_t)64 * D_MODEL;
            kreg = *(const bf16x8*)kptr;
            vreg = *(const bf16x8*)vptr;
        }

        f32x4 st[4];
        __builtin_amdgcn_s_setprio(1);
        #pragma unroll
        for (int kt = 0; kt < 4; ++kt) {
            const int kr = (kt * 16 + l15) * 64;
            bf16x8 kf0 = *(const bf16x8*)&Ks[kr + krswz0];
            bf16x8 kf1 = *(const bf16x8*)&Ks[kr + krswz1];
            f32x4 z = {};
            z = __builtin_amdgcn_mfma_f32_16x16x32_bf16(kf0, qf0, z, 0, 0, 0);
            z = __builtin_amdgcn_mfma_f32_16x16x32_bf16(kf1, qf1, z, 0, 0, 0);
            st[kt] = z;
        }
        __builtin_amdgcn_s_setprio(0);

        float mx = st[0][0];
        #pragma unroll
        for (int kt = 0; kt < 4; ++kt)
            #pragma unroll
            for (int r = 0; r < 4; ++r)
                mx = fmaxf(mx, st[kt][r]);
        mx = fmaxf(mx, __shfl_xor(mx, 16));
        mx = fmaxf(mx, __shfl_xor(mx, 32));

        if (!__all(mx <= m_run + thr)) {
            const float mnew  = fmaxf(m_run, mx);
            const float alpha = __builtin_amdgcn_exp2f(m_run - mnew);
            m_run = mnew;
            l_run *= alpha;          // per-quad partial; alpha q-row-uniform
            float a[4];
            #pragma unroll
            for (int r = 0; r < 4; ++r)
                a[r] = __shfl(alpha, (lane & 48) | (quad * 4 + r));
            #pragma unroll
            for (int dt = 0; dt < 4; ++dt)
                #pragma unroll
                for (int r = 0; r < 4; ++r)
                    o[dt][r] *= a[r];
        }

        float rs = 0.f;
        #pragma unroll
        for (int kt = 0; kt < 4; ++kt) {
            float p0 = __builtin_amdgcn_exp2f(st[kt][0] - m_run);
            float p1 = __builtin_amdgcn_exp2f(st[kt][1] - m_run);
            float p2 = __builtin_amdgcn_exp2f(st[kt][2] - m_run);
            float p3 = __builtin_amdgcn_exp2f(st[kt][3] - m_run);
            rs += (p0 + p1) + (p2 + p3);
            uint2 pk;
            pk.x = (uint32_t)f2bf(p0) | ((uint32_t)f2bf(p1) << 16);
            pk.y = (uint32_t)f2bf(p2) | ((uint32_t)f2bf(p3) << 16);
            const int G = kt * 2 + (quad >> 1);
            *(uint2*)&Ps[w][l15 * 64 + ((G ^ (l15 & 7)) * 8) + (quad & 1) * 4] = pk;
        }
        l_run += rs;                 // deferred: reduce across quads at end

        __builtin_amdgcn_s_setprio(1);
        #pragma unroll
        for (int f = 0; f < 2; ++f) {
            bf16x8 pf = *(const bf16x8*)&Ps[w][l15 * 64 + (((f * 4 + quad) ^ (l15 & 7)) * 8)];
            #pragma unroll
            for (int dt = 0; dt < 4; ++dt) {
                bf16x8 vf = *(const bf16x8*)&Vs[(dt * 16 + l15) * 64 + (((f * 4 + quad) ^ (l15 & 7)) * 8)];
                o[dt] = __builtin_amdgcn_mfma_f32_16x16x32_bf16(pf, vf, o[dt], 0, 0, 0);
            }
        }
        __builtin_amdgcn_s_setprio(0);
    }

    // epilogue: reduce deferred per-quad l partials, then normalize
    l_run += __shfl_xor(l_run, 16);
    l_run += __shfl_xor(l_run, 32);
    const float inv = 1.f / l_run;
    #pragma unroll
    for (int r = 0; r < 4; ++r) {
        const float linv = __shfl(inv, (lane & 48) | (quad * 4 + r));
        const int row = q0 + w * 16 + quad * 4 + r;
        #pragma unroll
        for (int dt = 0; dt < 4; ++dt) {
            int col = h * DH + dt * 16 + l15;
            Ow[(size_t)row * D_MODEL + col] = (short)f2bf(o[dt][r] * linv);
        }
    }
}

extern "C" void kernel_launch(void* const* d_in, const int* in_sizes, int n_in,
                              void* d_out, int out_size, void* d_ws, size_t ws_size,
                              hipStream_t stream) {
    const float* Q   = (const float*)d_in[0];
    const float* K   = (const float*)d_in[1];
    const float* V   = (const float*)d_in[2];
    const float* w_q = (const float*)d_in[3];
    const float* b_q = (const float*)d_in[4];
    const float* w_k = (const float*)d_in[5];
    const float* b_k = (const float*)d_in[6];
    const float* w_v = (const float*)d_in[7];
    const float* b_v = (const float*)d_in[8];
    const float* w_o = (const float*)d_in[9];
    const float* b_o = (const float*)d_in[10];
    float* out = (float*)d_out;

    const int L = in_sizes[0] / D_MODEL;   // 4096
    const size_t mat = (size_t)L * D_MODEL;

    // Memory plan.
    // Fallback (ws >= 24 MB): d_ws [0,8): Wb | [8,16): a_ws | [16,24): v_ws;
    //   d_out [0,8): q_ws | [8,16): k_ws (dead before out_proj's fp32 C).
    // Extended (ws >= 40 MB, active since R5):
    //   d_ws [0,8): Wb | [8,16): Vb -> a_ws | [16,24): v_ws |
    //        [24,32): Qb | [32,40): Kb
    ushort* Wb   = (ushort*)d_ws;
    ushort* q_ws = (ushort*)d_out;
    ushort* k_ws = q_ws + mat;
    const bool ext = ws_size >= (size_t)40 * 1024 * 1024;

    ushort *a_ws, *v_ws, *Qb = nullptr, *Kb = nullptr, *Vb = nullptr;
    if (ext) {
        Vb   = (ushort*)d_ws + 4 * 1048576;   // [8,16)
        v_ws = Vb + mat;                      // [16,24)
        Qb   = v_ws + mat;                    // [24,32)
        Kb   = Qb + mat;                      // [32,40)
        a_ws = Vb;                            // reuse after qkv consumes Vb
    } else {
        a_ws = (ushort*)d_ws + 4 * 1048576;
        v_ws = a_ws + mat;
    }

    dim3 gqkv(D_MODEL / 128, L / 128, 3);
    if (ext) {
        const int igrp = (int)(mat / 8);
        const int total = 524288 + 3 * igrp;
        cvt_all_kernel<<<dim3((total + 255) / 256), dim3(256), 0, stream>>>(
            w_q, w_k, w_v, w_o, Q, K, V, Wb, Qb, Kb, Vb, igrp);
        qkv_proj_bf16_kernel<<<gqkv, dim3(256), 0, stream>>>(Qb, Kb, Vb, Wb,
                                                             b_q, b_k, b_v,
                                                             q_ws, k_ws, v_ws, L);
    } else {
        cvt_w_kernel<<<dim3(2048), dim3(256), 0, stream>>>(w_q, w_k, w_v, w_o, Wb);
        qkv_proj_f32_kernel<<<gqkv, dim3(256), 0, stream>>>(Q, K, V, Wb,
                                                            b_q, b_k, b_v,
                                                            q_ws, k_ws, v_ws, L);
    }
    dim3 gattn(L / 128, NHEAD);
    attn_kernel<<<gattn, dim3(512), 0, stream>>>(q_ws, k_ws, v_ws, a_ws, L);
    dim3 gout(D_MODEL / 128, L / 128);
    out_proj_kernel<<<gout, dim3(512), 0, stream>>>(a_ws, Wb, b_o, out, L);
}